// Round 9
// baseline (103.360 us; speedup 1.0000x reference)
//
#include <hip/hip_runtime.h>
#include <hip/hip_bf16.h>
#include <math.h>

#define L_SEQ 1024
#define TWO_L 2048
#define NHEAD 16
#define HD 64
#define DM 1024
#define BATCH 2

typedef _Float16 f16;
typedef _Float16 f16x4 __attribute__((ext_vector_type(4)));
typedef _Float16 f16x8 __attribute__((ext_vector_type(8)));
typedef float f32x4 __attribute__((ext_vector_type(4)));

// 8-elem f16 MFMA operand fragment: 4 contiguous halves at p, 4 at p+16
__device__ __forceinline__ f16x8 ld8(const f16* p) {
  f16x4 lo = *(const f16x4*)p;
  f16x4 hi = *(const f16x4*)(p + 16);
  f16x8 r;
  r[0] = lo[0]; r[1] = lo[1]; r[2] = lo[2]; r[3] = lo[3];
  r[4] = hi[0]; r[5] = hi[1]; r[6] = hi[2]; r[7] = hi[3];
  return r;
}

// ---------------- prep1: cvt x, cvt W, sinusoid table ----------------
__global__ __launch_bounds__(256) void prep1(const float* __restrict__ x,
                                             const float* __restrict__ W,
                                             float* __restrict__ pe,
                                             f16* __restrict__ peh,
                                             f16* __restrict__ xh,
                                             f16* __restrict__ Wh) {
  int bid = blockIdx.x, tid = threadIdx.x;
  if (bid < 2048) {
    int i = (bid * 256 + tid) * 4;
    float4 v = *(const float4*)(x + i);
    f16x4 o = {(f16)v.x, (f16)v.y, (f16)v.z, (f16)v.w};
    *(f16x4*)(xh + i) = o;
  } else if (bid < 4096) {
    int i = ((bid - 2048) * 256 + tid) * 4;
    float4 v = *(const float4*)(W + i);
    f16x4 o = {(f16)v.x, (f16)v.y, (f16)v.z, (f16)v.w};
    *(f16x4*)(Wh + i) = o;
  } else {
    int idx = (bid - 4096) * 256 + tid;   // 0..131071
    int l = idx >> 6, d = idx & 63;
    float posval = (float)(l - L_SEQ);
    float freq = expf(-(float)(d & 31) * 0.2971077539347156f);  // ln(10000)/31
    float ang = posval * freq;
    float v = (d < 32) ? sinf(ang) : cosf(ang);
    pe[idx] = v;
    peh[idx] = (f16)v;
  }
}

// ---------------- prep2: D[h][l] = rw[h].pe[l]; zero shifted diag ----------------
__global__ __launch_bounds__(256) void prep2(const float* __restrict__ rw,
                                             const float* __restrict__ pe,
                                             float* __restrict__ Dm,
                                             f16* __restrict__ F) {
  int bid = blockIdx.x, tid = threadIdx.x;
  if (bid < 128) {
    int idx = bid * 256 + tid;
    int h = idx >> 11, l = idx & (TWO_L - 1);
    float s = 0.f;
#pragma unroll
    for (int d = 0; d < HD; ++d) s = fmaf(rw[h * HD + d], pe[l * HD + d], s);
    Dm[idx] = s;
  } else {
    int idx = (bid - 128) * 256 + tid;    // bh*1024 + q
    int bh = idx >> 10, q = idx & 1023;
    if (q >= 1) F[((size_t)bh * L_SEQ + q) * L_SEQ + q - 1] = (f16)0.f;
  }
}

// ---------------- qv GEMM: 128x64 tiles, 2-phase async pipeline ----------------
#define QV_STEP(T, AS, BS, CA0, CA1, CA2, CA3, CB0, CB1, NA0, NA1, NA2, NA3, NB0, NB1) \
  {                                                                            \
    *(f16x8*)&AS[ra * 72 + ca] = CA0;                                          \
    *(f16x8*)&AS[ra * 72 + ca + 8] = CA1;                                      \
    *(f16x8*)&AS[ra * 72 + ca + 16] = CA2;                                     \
    *(f16x8*)&AS[ra * 72 + ca + 24] = CA3;                                     \
    *(f16x8*)&BS[rb * 72 + cb] = CB0;                                          \
    *(f16x8*)&BS[rb * 72 + cb + 8] = CB1;                                      \
    __syncthreads();                                                           \
    if ((T) + 1 < 16) {                                                        \
      const f16* na = ga + ((T) + 1) * 64;                                     \
      NA0 = *(const f16x8*)na;                                                 \
      NA1 = *(const f16x8*)(na + 8);                                           \
      NA2 = *(const f16x8*)(na + 16);                                          \
      NA3 = *(const f16x8*)(na + 24);                                          \
      const f16* nb = gb + ((T) + 1) * 64;                                     \
      NB0 = *(const f16x8*)nb;                                                 \
      NB1 = *(const f16x8*)(nb + 8);                                           \
    }                                                                          \
    __builtin_amdgcn_s_setprio(1);                                             \
    _Pragma("unroll")                                                          \
    for (int kc = 0; kc < 2; ++kc) {                                           \
      f16x8 am0 = ld8(&AS[(w * 32 + li) * 72 + kc * 32 + g * 4]);              \
      f16x8 am1 = ld8(&AS[(w * 32 + 16 + li) * 72 + kc * 32 + g * 4]);         \
      _Pragma("unroll")                                                        \
      for (int nf = 0; nf < 4; ++nf) {                                         \
        f16x8 bfr = ld8(&BS[(nf * 16 + li) * 72 + kc * 32 + g * 4]);           \
        s[0][nf] = __builtin_amdgcn_mfma_f32_16x16x32_f16(am0, bfr, s[0][nf], 0, 0, 0); \
        s[1][nf] = __builtin_amdgcn_mfma_f32_16x16x32_f16(am1, bfr, s[1][nf], 0, 0, 0); \
      }                                                                        \
    }                                                                          \
    __builtin_amdgcn_s_setprio(0);                                             \
  }

__global__ __launch_bounds__(256) void qv_mfma(const f16* __restrict__ xh,
                                               const f16* __restrict__ Wh,
                                               f16* __restrict__ qvh,
                                               f16* __restrict__ vT) {
  __shared__ f16 As0[128 * 72], As1[128 * 72];
  __shared__ f16 Bs0[64 * 72], Bs1[64 * 72];
  int tid = threadIdx.x;
  int w = tid >> 6, lane = tid & 63, g = lane >> 4, li = lane & 15;
  int m0 = blockIdx.y * 128, n0 = blockIdx.x * 64;
  int ra = tid >> 1, ca = (tid & 1) * 32;
  int rb = tid >> 2, cb = (tid & 3) * 16;

  const f16* ga = xh + (size_t)(m0 + ra) * 1024 + ca;
  const f16* gb = Wh + (size_t)(n0 + rb) * 1024 + cb;
  f16x8 ca0 = *(const f16x8*)ga, ca1 = *(const f16x8*)(ga + 8);
  f16x8 ca2 = *(const f16x8*)(ga + 16), ca3 = *(const f16x8*)(ga + 24);
  f16x8 cb0 = *(const f16x8*)gb, cb1 = *(const f16x8*)(gb + 8);
  f16x8 na0, na1, na2, na3, nb0, nb1;

  f32x4 s[2][4];
#pragma unroll
  for (int i = 0; i < 2; ++i)
#pragma unroll
    for (int j = 0; j < 4; ++j) s[i][j] = {0.f, 0.f, 0.f, 0.f};

  for (int t = 0; t < 16; t += 2) {
    QV_STEP(t, As0, Bs0, ca0, ca1, ca2, ca3, cb0, cb1, na0, na1, na2, na3, nb0, nb1);
    QV_STEP(t + 1, As1, Bs1, na0, na1, na2, na3, nb0, nb1, ca0, ca1, ca2, ca3, cb0, cb1);
  }

#pragma unroll
  for (int mb = 0; mb < 2; ++mb) {
#pragma unroll
    for (int nf = 0; nf < 4; ++nf) {
      int n = n0 + nf * 16 + li;
#pragma unroll
      for (int rr2 = 0; rr2 < 4; ++rr2) {
        int m = m0 + w * 32 + mb * 16 + g * 4 + rr2;
        f16 val = (f16)s[mb][nf][rr2];
        if (n < 1024) {
          qvh[(size_t)m * 2048 + n] = val;
        } else {
          int b_ = m >> 10, ls = m & 1023, hd = n - 1024;
          vT[((size_t)(b_ * 16 + (hd >> 6)) * 64 + (hd & 63)) * 1024 + ls] = val;
        }
      }
    }
  }
}

// ---------------- F GEMM v3 (R6): block per (bh, q-block, j-half), pipelined j-loop ----------------
__global__ __launch_bounds__(256) void f_gemm(const f16* __restrict__ qvh,
                                              const f16* __restrict__ peh,
                                              const float* __restrict__ Dm,
                                              f16* __restrict__ F) {
  __shared__ f16 Qs[64 * 72];
  __shared__ f16 Ps0[64 * 72], Ps1[64 * 72];
  int tid = threadIdx.x;
  int w = tid >> 6, lane = tid & 63, g = lane >> 4, li = lane & 15;
  int bh = blockIdx.y, b = bh >> 4, h = bh & 15;
  int qb = blockIdx.x >> 1, js = blockIdx.x & 1;
  int q0 = qb * 64;
  int t16 = 16 - qb;
  int ji0 = js ? 9 : 0;
  int ji1 = js ? 17 : 9;
  int r = tid >> 2, c = (tid & 3) * 16;

  const f16* sq = qvh + (size_t)(b * L_SEQ + q0 + r) * 2048 + h * HD + c;
  *(f16x8*)&Qs[r * 72 + c] = *(const f16x8*)sq;
  *(f16x8*)&Qs[r * 72 + c + 8] = *(const f16x8*)(sq + 8);

#define FJ0(JI) ((JI) < t16 ? (JI) * 64 : 1984 - q0 + ((JI) - t16) * 64)

  int jn = FJ0(ji0);
  f16x8 cp0 = *(const f16x8*)(peh + (size_t)(jn + r) * HD + c);
  f16x8 cp1 = *(const f16x8*)(peh + (size_t)(jn + r) * HD + c + 8);

  for (int ji = ji0; ji < ji1; ++ji) {
    f16* Ps = (ji & 1) ? Ps1 : Ps0;
    int j0 = FJ0(ji);
    *(f16x8*)&Ps[r * 72 + c] = cp0;
    *(f16x8*)&Ps[r * 72 + c + 8] = cp1;
    __syncthreads();
    if (ji + 1 < ji1) {
      jn = FJ0(ji + 1);
      cp0 = *(const f16x8*)(peh + (size_t)(jn + r) * HD + c);
      cp1 = *(const f16x8*)(peh + (size_t)(jn + r) * HD + c + 8);
    }
    float dvv[4];
#pragma unroll
    for (int nf = 0; nf < 4; ++nf) dvv[nf] = Dm[h * TWO_L + j0 + nf * 16 + li];
    f32x4 s[4];
#pragma unroll
    for (int i = 0; i < 4; ++i) s[i] = {0.f, 0.f, 0.f, 0.f};
    __builtin_amdgcn_s_setprio(1);
#pragma unroll
    for (int kc = 0; kc < 2; ++kc) {
      f16x8 a = ld8(&Qs[(w * 16 + li) * 72 + kc * 32 + g * 4]);
#pragma unroll
      for (int nf = 0; nf < 4; ++nf) {
        f16x8 bfr = ld8(&Ps[(nf * 16 + li) * 72 + kc * 32 + g * 4]);
        s[nf] = __builtin_amdgcn_mfma_f32_16x16x32_f16(a, bfr, s[nf], 0, 0, 0);
      }
    }
    __builtin_amdgcn_s_setprio(0);
#pragma unroll
    for (int nf = 0; nf < 4; ++nf) {
      int j = j0 + nf * 16 + li;
#pragma unroll
      for (int rr2 = 0; rr2 < 4; ++rr2) {
        int q = q0 + w * 16 + g * 4 + rr2;
        float val = s[nf][rr2] + dvv[nf];
        if (j < L_SEQ - q) {
          F[((size_t)bh * L_SEQ + q) * L_SEQ + q + j] = (f16)val;
        } else if (j >= TWO_L - q && q < L_SEQ - 1) {
          F[((size_t)bh * L_SEQ + q + 1) * L_SEQ + (j - TWO_L + q)] = (f16)val;
        }
      }
    }
  }
#undef FJ0
}

// ---------------- fused attention partial (split-K over 2 halves) ----------------
#define ATTN_STEP(T, KS, VS, CK0, CK1, CV0, CV1, NK0, NK1, NV0, NV1, CF, NF)   \
  {                                                                            \
    const int k0 = (T) * 64;                                                   \
    *(f16x8*)&KS[r * 72 + c] = CK0;                                            \
    *(f16x8*)&KS[r * 72 + c + 8] = CK1;                                        \
    *(f16x8*)&VS[r * 72 + c] = CV0;                                            \
    *(f16x8*)&VS[r * 72 + c + 8] = CV1;                                        \
    __syncthreads();                                                           \
    if ((T) + 1 < tend) {                                                      \
      const f16* nk = gk + (size_t)((T) + 1) * 64 * 1024;                      \
      NK0 = *(const f16x8*)nk;                                                 \
      NK1 = *(const f16x8*)(nk + 8);                                           \
      const f16* nv = gv + ((T) + 1) * 64;                                     \
      NV0 = *(const f16x8*)nv;                                                 \
      NV1 = *(const f16x8*)(nv + 8);                                           \
      _Pragma("unroll")                                                        \
      for (int kf = 0; kf < 4; ++kf)                                           \
        NF[kf] = *(const f16x4*)(Fq + ((T) + 1) * 64 + kf * 16 + g * 4);       \
    }                                                                          \
    f32x4 s[4];                                                                \
    _Pragma("unroll")                                                          \
    for (int i = 0; i < 4; ++i) s[i] = {0.f, 0.f, 0.f, 0.f};                   \
    __builtin_amdgcn_s_setprio(1);                                             \
    _Pragma("unroll")                                                          \
    for (int kc = 0; kc < 2; ++kc) {                                           \
      f16x8 qb = ld8(&Qs[(w * 16 + li) * 72 + kc * 32 + g * 4]);               \
      _Pragma("unroll")                                                        \
      for (int kf = 0; kf < 4; ++kf) {                                         \
        f16x8 ka = ld8(&KS[(kf * 16 + li) * 72 + kc * 32 + g * 4]);            \
        s[kf] = __builtin_amdgcn_mfma_f32_16x16x32_f16(ka, qb, s[kf], 0, 0, 0);\
      }                                                                        \
    }                                                                          \
    __builtin_amdgcn_s_setprio(0);                                             \
    float sv[16];                                                              \
    float tmax = -1e30f;                                                       \
    _Pragma("unroll")                                                          \
    for (int kf = 0; kf < 4; ++kf) {                                           \
      _Pragma("unroll")                                                        \
      for (int rr2 = 0; rr2 < 4; ++rr2) {                                      \
        float v_ = s[kf][rr2] + (float)CF[kf][rr2] +                           \
                   Ms[k0 + kf * 16 + g * 4 + rr2];                             \
        sv[kf * 4 + rr2] = v_;                                                 \
        tmax = fmaxf(tmax, v_);                                                \
      }                                                                        \
    }                                                                          \
    tmax = fmaxf(tmax, __shfl_xor(tmax, 16));                                  \
    tmax = fmaxf(tmax, __shfl_xor(tmax, 32));                                  \
    float mnew = fmaxf(m_run, tmax);                                           \
    float scale = __expf(m_run - mnew);                                        \
    m_run = mnew;                                                              \
    l_run *= scale;                                                            \
    _Pragma("unroll")                                                          \
    for (int f = 0; f < 4; ++f) {                                              \
      o[f][0] *= scale; o[f][1] *= scale; o[f][2] *= scale; o[f][3] *= scale;  \
    }                                                                          \
    float pf[16];                                                              \
    float lloc = 0.f;                                                          \
    _Pragma("unroll")                                                          \
    for (int i = 0; i < 16; ++i) { pf[i] = __expf(sv[i] - mnew); lloc += pf[i]; } \
    l_run += lloc;                                                             \
    f16x8 pb0, pb1;                                                            \
    _Pragma("unroll")                                                          \
    for (int i = 0; i < 8; ++i) { pb0[i] = (f16)pf[i]; pb1[i] = (f16)pf[8 + i]; } \
    __builtin_amdgcn_s_setprio(1);                                             \
    _Pragma("unroll")                                                          \
    for (int f = 0; f < 4; ++f) {                                              \
      f16x8 va0 = ld8(&VS[(f * 16 + li) * 72 + g * 4]);                        \
      o[f] = __builtin_amdgcn_mfma_f32_16x16x32_f16(va0, pb0, o[f], 0, 0, 0);  \
      f16x8 va1 = ld8(&VS[(f * 16 + li) * 72 + 32 + g * 4]);                   \
      o[f] = __builtin_amdgcn_mfma_f32_16x16x32_f16(va1, pb1, o[f], 0, 0, 0);  \
    }                                                                          \
    __builtin_amdgcn_s_setprio(0);                                             \
  }

__global__ __launch_bounds__(256) void attn_mfma(const f16* __restrict__ xh,
                                                 const f16* __restrict__ qvh,
                                                 const f16* __restrict__ vT,
                                                 const f16* __restrict__ F,
                                                 const int* __restrict__ mask,
                                                 const float* __restrict__ rr,
                                                 float* __restrict__ opart,
                                                 float* __restrict__ mlbuf) {
  __shared__ f16 Qs[64 * 72];
  __shared__ f16 Ks0[64 * 72], Ks1[64 * 72];
  __shared__ f16 Vs0[64 * 72], Vs1[64 * 72];
  __shared__ float Ms[L_SEQ];
  int tid = threadIdx.x;
  int w = tid >> 6, lane = tid & 63, g = lane >> 4, li = lane & 15;
  int bh = blockIdx.y, b = bh >> 4, h = bh & 15;
  int q0 = blockIdx.x * 64;
  int kh = blockIdx.z;
  int t0 = kh * 8, tend = t0 + 8;
  int r = tid >> 2, c = (tid & 3) * 16;

  // additive mask vector (full range; only [t0*64, tend*64) used)
#pragma unroll
  for (int i = 0; i < 4; ++i) {
    int k = tid + i * 256;
    Ms[k] = mask[b * L_SEQ + k] ? 0.f : -1e30f;
  }
  // Q (+r_r_bias)
  {
    const f16* src = qvh + (size_t)(b * L_SEQ + q0 + r) * 2048 + h * HD + c;
#pragma unroll
    for (int u = 0; u < 16; ++u)
      Qs[r * 72 + c + u] = (f16)((float)src[u] + rr[h * HD + c + u]);
  }

  int qrow = q0 + w * 16 + li;
  const f16* Fq = F + ((size_t)bh * L_SEQ + qrow) * L_SEQ;

  const f16* gk = xh + (size_t)(b * L_SEQ + r) * 1024 + h * HD + c;
  const f16* gv = vT + ((size_t)bh * 64 + r) * 1024 + c;
  f16x8 cka = *(const f16x8*)(gk + (size_t)t0 * 64 * 1024);
  f16x8 ckb = *(const f16x8*)(gk + (size_t)t0 * 64 * 1024 + 8);
  f16x8 cva = *(const f16x8*)(gv + t0 * 64);
  f16x8 cvb = *(const f16x8*)(gv + t0 * 64 + 8);
  f16x8 nka, nkb, nva, nvb;
  f16x4 cfv[4], nfv[4];
#pragma unroll
  for (int kf = 0; kf < 4; ++kf)
    cfv[kf] = *(const f16x4*)(Fq + t0 * 64 + kf * 16 + g * 4);

  float m_run = -1e30f, l_run = 0.f;
  f32x4 o[4];
#pragma unroll
  for (int i = 0; i < 4; ++i) o[i] = {0.f, 0.f, 0.f, 0.f};

  for (int t = t0; t < tend; t += 2) {
    ATTN_STEP(t, Ks0, Vs0, cka, ckb, cva, cvb, nka, nkb, nva, nvb, cfv, nfv);
    ATTN_STEP(t + 1, Ks1, Vs1, nka, nkb, nva, nvb, cka, ckb, cva, cvb, nfv, cfv);
  }

  float lt = l_run;
  lt += __shfl_xor(lt, 16);
  lt += __shfl_xor(lt, 32);
  // unnormalized partial O + (m, l)
  size_t prow = (size_t)(kh * 32 + bh) * L_SEQ + qrow;
  float* op = opart + prow * 64;
#pragma unroll
  for (int f = 0; f < 4; ++f) {
    float4 res = {o[f][0], o[f][1], o[f][2], o[f][3]};
    *(float4*)(op + f * 16 + g * 4) = res;
  }
  if (g == 0) {
    mlbuf[prow * 2] = m_run;
    mlbuf[prow * 2 + 1] = lt;
  }
}

// ---------------- combine the two K-halves ----------------
__global__ __launch_bounds__(256) void combine(const float* __restrict__ opart,
                                               const float* __restrict__ mlbuf,
                                               float* __restrict__ out) {
  int gid = blockIdx.x * 256 + threadIdx.x;
  int e = gid * 4;                     // over 32*1024*64 floats
  int qh = e >> 6;                     // bh*1024 + q
  int d0 = e & 63;
  float m0v = mlbuf[(size_t)qh * 2], l0v = mlbuf[(size_t)qh * 2 + 1];
  float m1v = mlbuf[(size_t)(32768 + qh) * 2], l1v = mlbuf[(size_t)(32768 + qh) * 2 + 1];
  float4 o0 = *(const float4*)(opart + (size_t)qh * 64 + d0);
  float4 o1 = *(const float4*)(opart + (size_t)(32768 + qh) * 64 + d0);
  float M = fmaxf(m0v, m1v);
  float w0 = __expf(m0v - M), w1 = __expf(m1v - M);
  float inv = 1.0f / (l0v * w0 + l1v * w1);
  int bh = qh >> 10, q = qh & 1023;
  int b = bh >> 4, h = bh & 15;
  float4 res = {(o0.x * w0 + o1.x * w1) * inv, (o0.y * w0 + o1.y * w1) * inv,
                (o0.z * w0 + o1.z * w1) * inv, (o0.w * w0 + o1.w * w1) * inv};
  *(float4*)(out + (size_t)(b * L_SEQ + q) * DM + h * HD + d0) = res;
}

extern "C" void kernel_launch(void* const* d_in, const int* in_sizes, int n_in,
                              void* d_out, int out_size, void* d_ws, size_t ws_size,
                              hipStream_t stream) {
  const float* x = (const float*)d_in[0];
  const int* mask = (const int*)d_in[1];
  const float* W = (const float*)d_in[2];
  const float* rr = (const float*)d_in[3];
  const float* rw = (const float*)d_in[4];
  float* out = (float*)d_out;

  float* ws = (float*)d_ws;
  float* pe = ws;                                    // 131072 f32
  float* Dm = pe + 131072;                           // 32768 f32
  f16* peh = (f16*)(Dm + 32768);                     // 131072 f16
  f16* xh = peh + 131072;                            // 2M f16
  f16* Wh = xh + 2097152;                            // 2M f16
  f16* qvh = Wh + 2097152;                           // 4M f16
  f16* vT = qvh + 4194304;                           // 2M f16
  f16* F = vT + 2097152;                             // 32M f16 (64 MB)
  float* opart = (float*)(F + 33554432);             // 2*32768*64 f32 (16.8 MB)
  float* mlbuf = opart + 4194304;                    // 2*32768*2 f32

  prep1<<<4608, 256, 0, stream>>>(x, W, pe, peh, xh, Wh);
  prep2<<<256, 256, 0, stream>>>(rw, pe, Dm, F);
  qv_mfma<<<dim3(32, 16), 256, 0, stream>>>(xh, Wh, qvh, vT);
  f_gemm<<<dim3(32, 32), 256, 0, stream>>>(qvh, peh, Dm, F);
  attn_mfma<<<dim3(16, 32, 2), 256, 0, stream>>>(xh, qvh, vT, F, mask, rr, opart, mlbuf);
  combine<<<2048, 256, 0, stream>>>(opart, mlbuf, out);
}

// Round 10
// 85.582 us; speedup vs baseline: 1.2077x; 1.2077x over previous
//
#include <hip/hip_runtime.h>
#include <hip/hip_bf16.h>
#include <math.h>

#define L_SEQ 1024
#define TWO_L 2048
#define NHEAD 16
#define HD 64
#define DM 1024
#define BATCH 2
// pe2: 2176 rows, row r <-> u = r-1088, value = pe_ext[u mod 2049];
// pe_ext[j] = pe[j] for j<2048, pe_ext[2048] = 0 (shifted-diagonal zero row).
#define PE2R 2176

typedef _Float16 f16;
typedef _Float16 f16x4 __attribute__((ext_vector_type(4)));
typedef _Float16 f16x8 __attribute__((ext_vector_type(8)));
typedef float f32x4 __attribute__((ext_vector_type(4)));

// 8-elem f16 MFMA operand fragment: 4 contiguous halves at p, 4 at p+16
__device__ __forceinline__ f16x8 ld8(const f16* p) {
  f16x4 lo = *(const f16x4*)p;
  f16x4 hi = *(const f16x4*)(p + 16);
  f16x8 r;
  r[0] = lo[0]; r[1] = lo[1]; r[2] = lo[2]; r[3] = lo[3];
  r[4] = hi[0]; r[5] = hi[1]; r[6] = hi[2]; r[7] = hi[3];
  return r;
}

__device__ __forceinline__ float pe_val(int j, int d) {
  float posval = (float)(j - L_SEQ);
  float freq = expf(-(float)(d & 31) * 0.2971077539347156f);  // ln(10000)/31
  float ang = posval * freq;
  return (d < 32) ? sinf(ang) : cosf(ang);
}

// ---------------- prep1: cvt x, cvt W, pe2 extended table ----------------
__global__ __launch_bounds__(256) void prep1(const float* __restrict__ x,
                                             const float* __restrict__ W,
                                             f16* __restrict__ pe2,
                                             f16* __restrict__ xh,
                                             f16* __restrict__ Wh) {
  int bid = blockIdx.x, tid = threadIdx.x;
  if (bid < 2048) {
    int i = (bid * 256 + tid) * 4;
    float4 v = *(const float4*)(x + i);
    f16x4 o = {(f16)v.x, (f16)v.y, (f16)v.z, (f16)v.w};
    *(f16x4*)(xh + i) = o;
  } else if (bid < 4096) {
    int i = ((bid - 2048) * 256 + tid) * 4;
    float4 v = *(const float4*)(W + i);
    f16x4 o = {(f16)v.x, (f16)v.y, (f16)v.z, (f16)v.w};
    *(f16x4*)(Wh + i) = o;
  } else {
    int idx = (bid - 4096) * 256 + tid;   // 0..PE2R*64-1
    int rrow = idx >> 6, d = idx & 63;
    int u = rrow - 1088;
    int j = (u < 0) ? u + 2049 : u;       // in [0, 2048]
    float v = (j != 2048) ? pe_val(j, d) : 0.f;
    pe2[idx] = (f16)v;
  }
}

// ---------------- qv GEMM (R6: 64x64, 2-phase async pipeline) ----------------
#define QV_STEP(T, AS, BS, CA0, CA1, CB0, CB1, NA0, NA1, NB0, NB1)             \
  {                                                                            \
    *(f16x8*)&AS[r * 72 + c] = CA0;                                            \
    *(f16x8*)&AS[r * 72 + c + 8] = CA1;                                        \
    *(f16x8*)&BS[r * 72 + c] = CB0;                                            \
    *(f16x8*)&BS[r * 72 + c + 8] = CB1;                                        \
    __syncthreads();                                                           \
    if ((T) + 1 < 16) {                                                        \
      const f16* na = ga + ((T) + 1) * 64;                                     \
      NA0 = *(const f16x8*)na;                                                 \
      NA1 = *(const f16x8*)(na + 8);                                           \
      const f16* nb = gb + ((T) + 1) * 64;                                     \
      NB0 = *(const f16x8*)nb;                                                 \
      NB1 = *(const f16x8*)(nb + 8);                                           \
    }                                                                          \
    _Pragma("unroll")                                                          \
    for (int kc = 0; kc < 2; ++kc) {                                           \
      f16x8 a = ld8(&AS[(w * 16 + li) * 72 + kc * 32 + g * 4]);                \
      _Pragma("unroll")                                                        \
      for (int nf = 0; nf < 4; ++nf) {                                         \
        f16x8 bfr = ld8(&BS[(nf * 16 + li) * 72 + kc * 32 + g * 4]);           \
        s[nf] = __builtin_amdgcn_mfma_f32_16x16x32_f16(a, bfr, s[nf], 0, 0, 0);\
      }                                                                        \
    }                                                                          \
  }

__global__ __launch_bounds__(256) void qv_mfma(const f16* __restrict__ xh,
                                               const f16* __restrict__ Wh,
                                               f16* __restrict__ qvh,
                                               f16* __restrict__ vT) {
  __shared__ f16 As0[64 * 72], As1[64 * 72];
  __shared__ f16 Bs0[64 * 72], Bs1[64 * 72];
  int tid = threadIdx.x;
  int w = tid >> 6, lane = tid & 63, g = lane >> 4, li = lane & 15;
  int m0 = blockIdx.y * 64, n0 = blockIdx.x * 64;
  int r = tid >> 2, c = (tid & 3) * 16;

  const f16* ga = xh + (size_t)(m0 + r) * 1024 + c;
  const f16* gb = Wh + (size_t)(n0 + r) * 1024 + c;
  f16x8 ca0 = *(const f16x8*)ga, ca1 = *(const f16x8*)(ga + 8);
  f16x8 cb0 = *(const f16x8*)gb, cb1 = *(const f16x8*)(gb + 8);
  f16x8 na0, na1, nb0, nb1;

  f32x4 s[4];
#pragma unroll
  for (int i = 0; i < 4; ++i) s[i] = {0.f, 0.f, 0.f, 0.f};

  for (int t = 0; t < 16; t += 2) {
    QV_STEP(t, As0, Bs0, ca0, ca1, cb0, cb1, na0, na1, nb0, nb1);
    QV_STEP(t + 1, As1, Bs1, na0, na1, nb0, nb1, ca0, ca1, cb0, cb1);
  }

#pragma unroll
  for (int nf = 0; nf < 4; ++nf) {
    int n = n0 + nf * 16 + li;
#pragma unroll
    for (int rr2 = 0; rr2 < 4; ++rr2) {
      int m = m0 + w * 16 + g * 4 + rr2;
      f16 val = (f16)s[nf][rr2];
      if (n < 1024) {
        qvh[(size_t)m * 2048 + n] = val;
      } else {
        int b_ = m >> 10, ls = m & 1023, hd = n - 1024;
        vT[((size_t)(b_ * 16 + (hd >> 6)) * 64 + (hd & 63)) * 1024 + ls] = val;
      }
    }
  }
}

// ---------------- fused attention with rolling 64-wide relative-position band ----------------
// Band value: G[u][q] = (q_vec(row) + rw) . pe_ext[u mod 2049], row = q for u>=0, q-1 for u<0.
// Circular band buffer Gb[64q][136], logical col(u) = (u + q0) & 127. Per k-tile t: window
// u in [64t - q0, 64t - q0 + 64) -> cols (64t&127)+[0,64). Prologue window [-q0-64, -q0).
// Gather: F[q][k] = Gb[qlocal][(64t + (k-k0) - qlocal) & 127-ish]; all values +Ms mask.
#define BANDFILL(TT, QOFF, PEREG)                                              \
  {                                                                            \
    _Pragma("unroll")                                                          \
    for (int qf = 0; qf < 4; ++qf) {                                           \
      f32x4 gacc = {0.f, 0.f, 0.f, 0.f};                                       \
      _Pragma("unroll")                                                        \
      for (int kc = 0; kc < 2; ++kc) {                                         \
        f16x8 qo = ld8(&Qw[((QOFF) + qf * 16 + li) * 72 + kc * 32 + g * 4]);   \
        gacc = __builtin_amdgcn_mfma_f32_16x16x32_f16(PEREG[kc], qo, gacc, 0, 0, 0); \
      }                                                                        \
      f16x4 gpk;                                                               \
      gpk[0] = (f16)gacc[0]; gpk[1] = (f16)gacc[1];                            \
      gpk[2] = (f16)gacc[2]; gpk[3] = (f16)gacc[3];                            \
      *(f16x4*)&Gb[(qf * 16 + li) * 136 + (TT) + w * 16 + g * 4] = gpk;        \
    }                                                                          \
  }

#define ATTN_STEP(T, KS, VS, CK0, CK1, CV0, CV1, NK0, NK1, NV0, NV1, CPE, NPE) \
  {                                                                            \
    const int k0 = (T) * 64;                                                   \
    const int tt = (64 * (T)) & 127;                                           \
    const int qoff = (64 * (T) >= q0) ? 1 : 0;                                 \
    *(f16x8*)&KS[r * 72 + c] = CK0;                                            \
    *(f16x8*)&KS[r * 72 + c + 8] = CK1;                                        \
    *(f16x8*)&VS[r * 72 + c] = CV0;                                            \
    *(f16x8*)&VS[r * 72 + c + 8] = CV1;                                        \
    BANDFILL(tt, qoff, CPE)                                                    \
    __syncthreads();                                                           \
    if ((T) + 1 < 16) {                                                        \
      const f16* nk = gk + (size_t)((T) + 1) * 64 * 1024;                      \
      NK0 = *(const f16x8*)nk;                                                 \
      NK1 = *(const f16x8*)(nk + 8);                                           \
      const f16* nv = gv + ((T) + 1) * 64;                                     \
      NV0 = *(const f16x8*)nv;                                                 \
      NV1 = *(const f16x8*)(nv + 8);                                           \
      const f16* pb = pe2 + (size_t)(1088 + 64 * ((T) + 1) - q0 + w * 16 + li) * 64; \
      NPE[0] = ld8(pb + g * 4);                                                \
      NPE[1] = ld8(pb + 32 + g * 4);                                           \
    }                                                                          \
    float gf[16];                                                              \
    {                                                                          \
      const int cb0 = tt + g * 4 - qi + 128;                                   \
      _Pragma("unroll")                                                        \
      for (int kf = 0; kf < 4; ++kf)                                           \
        _Pragma("unroll")                                                      \
        for (int u2 = 0; u2 < 4; ++u2)                                         \
          gf[kf * 4 + u2] = (float)Gb[qi * 136 + ((cb0 + kf * 16 + u2) & 127)];\
    }                                                                          \
    f32x4 s[4];                                                                \
    _Pragma("unroll")                                                          \
    for (int i = 0; i < 4; ++i) s[i] = {0.f, 0.f, 0.f, 0.f};                   \
    __builtin_amdgcn_s_setprio(1);                                             \
    _Pragma("unroll")                                                          \
    for (int kc = 0; kc < 2; ++kc) {                                           \
      f16x8 qb = ld8(&Qs[(1 + w * 16 + li) * 72 + kc * 32 + g * 4]);           \
      _Pragma("unroll")                                                        \
      for (int kf = 0; kf < 4; ++kf) {                                         \
        f16x8 ka = ld8(&KS[(kf * 16 + li) * 72 + kc * 32 + g * 4]);            \
        s[kf] = __builtin_amdgcn_mfma_f32_16x16x32_f16(ka, qb, s[kf], 0, 0, 0);\
      }                                                                        \
    }                                                                          \
    __builtin_amdgcn_s_setprio(0);                                             \
    float sv[16];                                                              \
    float tmax = -1e30f;                                                       \
    _Pragma("unroll")                                                          \
    for (int kf = 0; kf < 4; ++kf) {                                           \
      _Pragma("unroll")                                                        \
      for (int rr2 = 0; rr2 < 4; ++rr2) {                                      \
        float v_ = s[kf][rr2] + gf[kf * 4 + rr2] +                             \
                   Ms[k0 + kf * 16 + g * 4 + rr2];                             \
        sv[kf * 4 + rr2] = v_;                                                 \
        tmax = fmaxf(tmax, v_);                                                \
      }                                                                        \
    }                                                                          \
    tmax = fmaxf(tmax, __shfl_xor(tmax, 16));                                  \
    tmax = fmaxf(tmax, __shfl_xor(tmax, 32));                                  \
    float mnew = fmaxf(m_run, tmax);                                           \
    float scale = __expf(m_run - mnew);                                        \
    m_run = mnew;                                                              \
    l_run *= scale;                                                            \
    _Pragma("unroll")                                                          \
    for (int f = 0; f < 4; ++f) {                                              \
      o[f][0] *= scale; o[f][1] *= scale; o[f][2] *= scale; o[f][3] *= scale;  \
    }                                                                          \
    float pf[16];                                                              \
    float lloc = 0.f;                                                          \
    _Pragma("unroll")                                                          \
    for (int i = 0; i < 16; ++i) { pf[i] = __expf(sv[i] - mnew); lloc += pf[i]; } \
    l_run += lloc;                                                             \
    f16x8 pb0, pb1;                                                            \
    _Pragma("unroll")                                                          \
    for (int i = 0; i < 8; ++i) { pb0[i] = (f16)pf[i]; pb1[i] = (f16)pf[8 + i]; } \
    __builtin_amdgcn_s_setprio(1);                                             \
    _Pragma("unroll")                                                          \
    for (int f = 0; f < 4; ++f) {                                              \
      f16x8 va0 = ld8(&VS[(f * 16 + li) * 72 + g * 4]);                        \
      o[f] = __builtin_amdgcn_mfma_f32_16x16x32_f16(va0, pb0, o[f], 0, 0, 0);  \
      f16x8 va1 = ld8(&VS[(f * 16 + li) * 72 + 32 + g * 4]);                   \
      o[f] = __builtin_amdgcn_mfma_f32_16x16x32_f16(va1, pb1, o[f], 0, 0, 0);  \
    }                                                                          \
    __builtin_amdgcn_s_setprio(0);                                             \
    __syncthreads();                                                           \
  }

__global__ __launch_bounds__(256) void attn_mfma(const f16* __restrict__ xh,
                                                 const f16* __restrict__ qvh,
                                                 const f16* __restrict__ vT,
                                                 const f16* __restrict__ pe2,
                                                 const int* __restrict__ mask,
                                                 const float* __restrict__ rr,
                                                 const float* __restrict__ rw,
                                                 float* __restrict__ out) {
  __shared__ f16 Qs[65 * 72];            // rows q0-1 .. q0+63, +r_r bias (QK^T)
  __shared__ f16 Qw[65 * 72];            // rows q0-1 .. q0+63, +r_w bias (band)
  __shared__ f16 Ks0[64 * 72], Ks1[64 * 72];
  __shared__ f16 Vs0[64 * 72], Vs1[64 * 72];
  __shared__ f16 Gb[64 * 136];           // circular band [qlocal][128 cols + pad]
  __shared__ float Ms[L_SEQ];
  int tid = threadIdx.x;
  int w = tid >> 6, lane = tid & 63, g = lane >> 4, li = lane & 15;
  int bh = blockIdx.y, b = bh >> 4, h = bh & 15;
  int q0 = blockIdx.x * 64;
  int r = tid >> 2, c = (tid & 3) * 16;
  const int qi = w * 16 + li;

  // additive mask vector
#pragma unroll
  for (int i = 0; i < 4; ++i) {
    int k = tid + i * 256;
    Ms[k] = mask[b * L_SEQ + k] ? 0.f : -1e30f;
  }
  // Q rows q0-1 .. q0+63: Qs = +rr (row i <-> q0-1+i), Qw = +rw. Row 0 clamped
  // (its band values correspond to k<0 and are never gathered).
  {
    int gq = q0 - 1 + r;
    if (gq < 0) gq = 0;
    const f16* src = qvh + (size_t)(b * L_SEQ + gq) * 2048 + h * HD + c;
#pragma unroll
    for (int u = 0; u < 16; ++u) {
      float v = (float)src[u];
      Qs[r * 72 + c + u] = (f16)(v + rr[h * HD + c + u]);
      Qw[r * 72 + c + u] = (f16)(v + rw[h * HD + c + u]);
    }
    if (tid < 4) {
      int c2 = tid * 16;
      const f16* s2 = qvh + (size_t)(b * L_SEQ + q0 + 63) * 2048 + h * HD + c2;
#pragma unroll
      for (int u = 0; u < 16; ++u) {
        float v = (float)s2[u];
        Qs[64 * 72 + c2 + u] = (f16)(v + rr[h * HD + c2 + u]);
        Qw[64 * 72 + c2 + u] = (f16)(v + rw[h * HD + c2 + u]);
      }
    }
  }

  // global prefetches: K/V tile 0, pe strips for prologue window and tile-0 window
  const f16* gk = xh + (size_t)(b * L_SEQ + r) * 1024 + h * HD + c;
  const f16* gv = vT + ((size_t)bh * 64 + r) * 1024 + c;
  f16x8 cka = *(const f16x8*)gk, ckb = *(const f16x8*)(gk + 8);
  f16x8 cva = *(const f16x8*)gv, cvb = *(const f16x8*)(gv + 8);
  f16x8 nka, nkb, nva, nvb;
  f16x8 peP[2], peA[2], peB[2];
  {
    const f16* pp = pe2 + (size_t)(1024 - q0 + w * 16 + li) * 64;   // prologue: u base -q0-64
    peP[0] = ld8(pp + g * 4);
    peP[1] = ld8(pp + 32 + g * 4);
    const f16* p0 = pe2 + (size_t)(1088 - q0 + w * 16 + li) * 64;   // tile 0: u base -q0
    peA[0] = ld8(p0 + g * 4);
    peA[1] = ld8(p0 + 32 + g * 4);
  }

  __syncthreads();   // Qs/Qw/Ms ready

  // prologue band: window [-q0-64, -q0) -> cols 64..127, wrap rows (qoff=0)
  BANDFILL(64, 0, peP)
  // (no barrier needed here: step 0's barrier covers Gb visibility)

  float m_run = -1e30f, l_run = 0.f;
  f32x4 o[4];
#pragma unroll
  for (int i = 0; i < 4; ++i) o[i] = {0.f, 0.f, 0.f, 0.f};

  for (int t = 0; t < 16; t += 2) {
    ATTN_STEP(t, Ks0, Vs0, cka, ckb, cva, cvb, nka, nkb, nva, nvb, peA, peB);
    ATTN_STEP(t + 1, Ks1, Vs1, nka, nkb, nva, nvb, cka, ckb, cva, cvb, peB, peA);
  }

  float lt = l_run;
  lt += __shfl_xor(lt, 16);
  lt += __shfl_xor(lt, 32);
  float inv = 1.0f / lt;
  int qrow = q0 + qi;
  float* op = out + ((size_t)(b * L_SEQ + qrow)) * DM + h * HD;
#pragma unroll
  for (int f = 0; f < 4; ++f) {
    float4 res = {o[f][0] * inv, o[f][1] * inv, o[f][2] * inv, o[f][3] * inv};
    *(float4*)(op + f * 16 + g * 4) = res;
  }
}

extern "C" void kernel_launch(void* const* d_in, const int* in_sizes, int n_in,
                              void* d_out, int out_size, void* d_ws, size_t ws_size,
                              hipStream_t stream) {
  const float* x = (const float*)d_in[0];
  const int* mask = (const int*)d_in[1];
  const float* W = (const float*)d_in[2];
  const float* rr = (const float*)d_in[3];
  const float* rw = (const float*)d_in[4];
  float* out = (float*)d_out;

  f16* pe2 = (f16*)d_ws;                             // 2176*64 f16
  f16* xh = pe2 + (size_t)PE2R * 64;                 // 2M f16
  f16* Wh = xh + 2097152;                            // 2M f16
  f16* qvh = Wh + 2097152;                           // 4M f16
  f16* vT = qvh + 4194304;                           // 2M f16

  prep1<<<4096 + (PE2R * 64) / 256, 256, 0, stream>>>(x, W, pe2, xh, Wh);
  qv_mfma<<<dim3(32, 32), 256, 0, stream>>>(xh, Wh, qvh, vT);
  attn_mfma<<<dim3(16, 32), 256, 0, stream>>>(xh, qvh, vT, pe2, mask, rr, rw, out);
}